// Round 1
// baseline (211.733 us; speedup 1.0000x reference)
//
#include <hip/hip_runtime.h>
#include <hip/hip_bf16.h>

#define CC 728
#define KPAD 768
#define M_ROWS 46208  // 32*38*38

typedef __attribute__((ext_vector_type(8))) short bf16x8;
typedef __attribute__((ext_vector_type(8))) unsigned short ushort8;
typedef __attribute__((ext_vector_type(4))) float f32x4;

// round-to-nearest-even fp32 -> bf16 bits
__device__ __forceinline__ unsigned short f2bf(float f) {
    unsigned int u = __float_as_uint(f);
    unsigned int r = u + 0x7fffu + ((u >> 16) & 1u);
    return (unsigned short)(r >> 16);
}

__device__ __forceinline__ void gload_lds16(const void* g, void* l) {
    __builtin_amdgcn_global_load_lds(
        (const __attribute__((address_space(1))) void*)g,
        (__attribute__((address_space(3))) void*)l,
        16, 0, 0);
}

// h[d] = (1/728) * sum_{k=182}^{545} cos(2*pi*k*d/728)
__global__ void build_h(float* __restrict__ h) {
    int m = blockIdx.x * blockDim.x + threadIdx.x;
    if (m >= CC) return;
    double s = 0.0;
    const double w = 6.283185307179586476925286766559 / (double)CC;
    for (int k = 182; k <= 545; ++k) {
        int t = (k * m) % CC;               // exact angle reduction
        s += cos(w * (double)t);
    }
    h[m] = (float)(s / (double)CC);
}

// Bt[n][k] = bf16(h[(n-k) mod 728]), zero-padded to 768x768, stride KPAD
__global__ void build_bt(const float* __restrict__ h, unsigned short* __restrict__ bt) {
    int idx = blockIdx.x * blockDim.x + threadIdx.x;
    if (idx >= KPAD * KPAD) return;
    int n = idx / KPAD, k = idx % KPAD;
    float v = 0.f;
    if (n < CC && k < CC) {
        int d = n - k;
        if (d < 0) d += CC;
        v = h[d];
    }
    bt[idx] = f2bf(v);
}

// X fp32 [M_ROWS][728] -> bf16 [M_ROWS][768] (zero-padded tail)
__global__ void convert_x(const float* __restrict__ x, unsigned short* __restrict__ xp) {
    int i = blockIdx.x * blockDim.x + threadIdx.x;   // M_ROWS * 96 threads-of-8
    if (i >= M_ROWS * (KPAD / 8)) return;
    int c8 = i % (KPAD / 8);
    int r  = i / (KPAD / 8);
    ushort8 o;
#pragma unroll
    for (int j = 0; j < 8; ++j) o[j] = 0;
    if (c8 < CC / 8) {  // 728/8 = 91 exactly
        const float4* px = (const float4*)(x + r * CC + c8 * 8);
        float4 v0 = px[0], v1 = px[1];
        o[0] = f2bf(v0.x); o[1] = f2bf(v0.y); o[2] = f2bf(v0.z); o[3] = f2bf(v0.w);
        o[4] = f2bf(v1.x); o[5] = f2bf(v1.y); o[6] = f2bf(v1.z); o[7] = f2bf(v1.w);
    }
    *(ushort8*)(xp + r * KPAD + c8 * 8) = o;
}

// 128x128 tile bf16 GEMM (m97 structure): Y = Xp @ Bt^T, fused ReLU, fp32 out
__global__ __launch_bounds__(256) void gemm_relu(
        const unsigned short* __restrict__ xp,
        const unsigned short* __restrict__ bt,
        float* __restrict__ out) {
    __shared__ unsigned short ldsA[128 * 32];
    __shared__ unsigned short ldsB[128 * 32];

    const int tid  = threadIdx.x;
    const int lane = tid & 63;
    const int wid  = tid >> 6;
    const int wr   = wid >> 1, wc = wid & 1;
    const int l15  = lane & 15, lhi = lane >> 4;
    const int bm   = blockIdx.y * 128;
    const int bn   = blockIdx.x * 128;

    f32x4 acc[4][4];
#pragma unroll
    for (int i = 0; i < 4; ++i)
#pragma unroll
        for (int j = 0; j < 4; ++j)
#pragma unroll
            for (int r = 0; r < 4; ++r) acc[i][j][r] = 0.f;

    const int row0 = tid >> 2;            // issue 0: rows 0..63
    const int kc   = (tid & 3) * 8;       // 8-elem (16B) column chunk

    for (int kt = 0; kt < KPAD / 32; ++kt) {
        const int k0 = kt * 32;
        // stage A-tile [128][32] and Bt-tile [128][32], 2 issues of 256x16B each
#pragma unroll
        for (int issue = 0; issue < 2; ++issue) {
            int s   = issue * 256 + tid;
            int row = issue * 64 + row0;
            gload_lds16(xp + (bm + row) * KPAD + k0 + kc, &ldsA[s * 8]);
            gload_lds16(bt + (bn + row) * KPAD + k0 + kc, &ldsB[s * 8]);
        }
        __syncthreads();   // compiler drains vmcnt before barrier

        bf16x8 a[4], b[4];
        const bf16x8* pA = (const bf16x8*)ldsA;
        const bf16x8* pB = (const bf16x8*)ldsB;
#pragma unroll
        for (int mi = 0; mi < 4; ++mi) a[mi] = pA[(wr * 64 + mi * 16 + l15) * 4 + lhi];
#pragma unroll
        for (int nj = 0; nj < 4; ++nj) b[nj] = pB[(wc * 64 + nj * 16 + l15) * 4 + lhi];

#pragma unroll
        for (int mi = 0; mi < 4; ++mi)
#pragma unroll
            for (int nj = 0; nj < 4; ++nj)
                acc[mi][nj] = __builtin_amdgcn_mfma_f32_16x16x32_bf16(
                    a[mi], b[nj], acc[mi][nj], 0, 0, 0);
        __syncthreads();
    }

    // epilogue: relu + fp32 store, guard n < 728
#pragma unroll
    for (int mi = 0; mi < 4; ++mi) {
#pragma unroll
        for (int nj = 0; nj < 4; ++nj) {
            int colg = bn + wc * 64 + nj * 16 + l15;
            if (colg < CC) {
#pragma unroll
                for (int r = 0; r < 4; ++r) {
                    int rowg = bm + wr * 64 + mi * 16 + lhi * 4 + r;
                    float v = acc[mi][nj][r];
                    out[rowg * CC + colg] = v > 0.f ? v : 0.f;
                }
            }
        }
    }
}

extern "C" void kernel_launch(void* const* d_in, const int* in_sizes, int n_in,
                              void* d_out, int out_size, void* d_ws, size_t ws_size,
                              hipStream_t stream) {
    const float* x = (const float*)d_in[0];
    float* out = (float*)d_out;

    char* ws = (char*)d_ws;
    float* h = (float*)ws;                                          // 728 f32
    unsigned short* bt = (unsigned short*)(ws + 4096);              // 768*768 bf16
    unsigned short* xp = (unsigned short*)(ws + 4096 + KPAD * KPAD * 2); // 46208*768 bf16

    build_h<<<12, 64, 0, stream>>>(h);
    build_bt<<<(KPAD * KPAD + 255) / 256, 256, 0, stream>>>(h, bt);
    convert_x<<<(M_ROWS * (KPAD / 8) + 255) / 256, 256, 0, stream>>>(x, xp);

    dim3 grid(KPAD / 128, M_ROWS / 128);   // 6 x 361
    gemm_relu<<<grid, 256, 0, stream>>>(xp, bt, out);
}

// Round 2
// 118.674 us; speedup vs baseline: 1.7842x; 1.7842x over previous
//
#include <hip/hip_runtime.h>
#include <hip/hip_bf16.h>

#define CC 728
#define KB 736          // padded K: 23 * 32
#define NPAD 768        // padded rows of Bt (6 * 128)
#define M_ROWS 46208    // 32*38*38
#define KT 23
#define NWG 2166        // (M_ROWS/128) * (NPAD/128) = 361*6

typedef __attribute__((ext_vector_type(8))) short bf16x8;
typedef __attribute__((ext_vector_type(8))) unsigned short ushort8;
typedef __attribute__((ext_vector_type(4))) float f32x4;

// round-to-nearest-even fp32 -> bf16 bits
__device__ __forceinline__ unsigned short f2bf(float f) {
    unsigned int u = __float_as_uint(f);
    unsigned int r = u + 0x7fffu + ((u >> 16) & 1u);
    return (unsigned short)(r >> 16);
}

__device__ __forceinline__ void gload_lds16(const void* g, void* l) {
    __builtin_amdgcn_global_load_lds(
        (const __attribute__((address_space(1))) void*)g,
        (__attribute__((address_space(3))) void*)l,
        16, 0, 0);
}

// Bt[n][k] = bf16(h[(n-k) mod 728]), closed form.
// h[0]=0.5; h[d]=0 for even d!=0; h[d odd] = s * cos(pi d/728)/(728 sin(pi d/728)),
// s = +1 if (d>>1)&1 else -1.   [matches validated round-0 sum]
__global__ void build_bt(unsigned short* __restrict__ bt) {
    int idx = blockIdx.x * blockDim.x + threadIdx.x;
    if (idx >= NPAD * KB) return;
    int n = idx / KB, k = idx % KB;
    float v = 0.f;
    if (n < CC && k < CC) {
        int d = n - k; if (d < 0) d += CC;
        if (d == 0) v = 0.5f;
        else if (d & 1) {
            float t = (float)(3.14159265358979323846 * (double)d / (double)CC);
            float s = ((d >> 1) & 1) ? 1.f : -1.f;
            v = s * cosf(t) / ((float)CC * sinf(t));
        }
    }
    bt[idx] = f2bf(v);
}

// Fused: Y = relu( fp32->bf16(X) @ Bt^T ), 128x128 tile, m97 2-barrier structure.
// A reg-staged (fp32 load + in-reg cvt + swizzled ds_write); B via global_load_lds
// with pre-swizzled global source. Frag reads use chunk rotation (c+(row>>1))&3.
__global__ __launch_bounds__(256) void gemm_relu(
        const float* __restrict__ x,
        const unsigned short* __restrict__ bt,
        float* __restrict__ out) {
    __shared__ unsigned short ldsA[128 * 32];
    __shared__ unsigned short ldsB[128 * 32];

    const int tid  = threadIdx.x;
    const int lane = tid & 63;
    const int wid  = tid >> 6;
    const int wr   = wid >> 1, wc = wid & 1;
    const int l15  = lane & 15, lhi = lane >> 4;

    // bijective XCD swizzle (m204): each XCD gets a contiguous wgid chunk,
    // bn cycles fastest within a chunk -> A-panel reused 6x from same L2.
    const int NX = 8;
    int orig  = blockIdx.x;
    int q = NWG / NX, r = NWG % NX;          // 270, 6
    int xcd = orig % NX, local = orig / NX;
    int wgid = (xcd < r ? xcd * (q + 1) : r * (q + 1) + (xcd - r) * q) + local;
    const int bm = (wgid / 6) * 128;
    const int bn = (wgid % 6) * 128;

    f32x4 acc[4][4];
#pragma unroll
    for (int i = 0; i < 4; ++i)
#pragma unroll
        for (int j = 0; j < 4; ++j)
#pragma unroll
            for (int rr = 0; rr < 4; ++rr) acc[i][j][rr] = 0.f;

    const int arow = tid >> 2;   // row within 64-row issue
    const int ac   = tid & 3;    // 16B(bf16)/32B(fp32) chunk id

    for (int kt = 0; kt < KT; ++kt) {
        const int k0 = kt * 32;

        // ---- B: async global->LDS, linear dest, pre-swizzled source chunk ----
#pragma unroll
        for (int i = 0; i < 2; ++i) {
            int rr   = i * 64 + arow;
            int gsrc = (ac - (rr >> 1)) & 3;
            gload_lds16(bt + (size_t)(bn + rr) * KB + k0 + gsrc * 8,
                        &ldsB[(i * 256 + tid) * 8]);
        }

        // ---- A: fp32 global -> regs ----
        float4 va0[2], va1[2];
        const bool full = (k0 + 32 <= CC);
#pragma unroll
        for (int i = 0; i < 2; ++i) {
            const float* src = x + (size_t)(bm + i * 64 + arow) * CC + k0 + ac * 8;
            if (full) {
                va0[i] = ((const float4*)src)[0];
                va1[i] = ((const float4*)src)[1];
            } else {
                int cb = k0 + ac * 8;
                va0[i] = (cb     < CC) ? ((const float4*)src)[0] : make_float4(0.f,0.f,0.f,0.f);
                va1[i] = (cb + 4 < CC) ? ((const float4*)src)[1] : make_float4(0.f,0.f,0.f,0.f);
            }
        }

        // ---- A: cvt + swizzled ds_write (chunk rotated by row>>1) ----
#pragma unroll
        for (int i = 0; i < 2; ++i) {
            int rr = i * 64 + arow;
            int sc = (ac + (rr >> 1)) & 3;
            ushort8 o;
            o[0] = f2bf(va0[i].x); o[1] = f2bf(va0[i].y);
            o[2] = f2bf(va0[i].z); o[3] = f2bf(va0[i].w);
            o[4] = f2bf(va1[i].x); o[5] = f2bf(va1[i].y);
            o[6] = f2bf(va1[i].z); o[7] = f2bf(va1[i].w);
            *(ushort8*)&ldsA[(rr * 4 + sc) * 8] = o;
        }
        __syncthreads();   // drains vmcnt (B in LDS) + lgkm (A writes)

        // ---- frags + MFMA ----
        bf16x8 a[4], b[4];
#pragma unroll
        for (int mi = 0; mi < 4; ++mi) {
            int row = wr * 64 + mi * 16 + l15;
            int c   = (lhi + (row >> 1)) & 3;
            a[mi] = *(const bf16x8*)&ldsA[(row * 4 + c) * 8];
        }
#pragma unroll
        for (int nj = 0; nj < 4; ++nj) {
            int row = wc * 64 + nj * 16 + l15;
            int c   = (lhi + (row >> 1)) & 3;
            b[nj] = *(const bf16x8*)&ldsB[(row * 4 + c) * 8];
        }
#pragma unroll
        for (int mi = 0; mi < 4; ++mi)
#pragma unroll
            for (int nj = 0; nj < 4; ++nj)
                acc[mi][nj] = __builtin_amdgcn_mfma_f32_16x16x32_bf16(
                    a[mi], b[nj], acc[mi][nj], 0, 0, 0);
        __syncthreads();
    }

    // ---- epilogue: relu + fp32 store, guard n < 728 ----
#pragma unroll
    for (int mi = 0; mi < 4; ++mi) {
#pragma unroll
        for (int nj = 0; nj < 4; ++nj) {
            int colg = bn + wc * 64 + nj * 16 + l15;
            if (colg < CC) {
#pragma unroll
                for (int rr = 0; rr < 4; ++rr) {
                    int rowg = bm + wr * 64 + mi * 16 + lhi * 4 + rr;
                    float v = acc[mi][nj][rr];
                    out[(size_t)rowg * CC + colg] = v > 0.f ? v : 0.f;
                }
            }
        }
    }
}

extern "C" void kernel_launch(void* const* d_in, const int* in_sizes, int n_in,
                              void* d_out, int out_size, void* d_ws, size_t ws_size,
                              hipStream_t stream) {
    const float* x = (const float*)d_in[0];
    float* out = (float*)d_out;

    unsigned short* bt = (unsigned short*)d_ws;   // NPAD*KB bf16 = 1.13 MB

    build_bt<<<(NPAD * KB + 255) / 256, 256, 0, stream>>>(bt);
    gemm_relu<<<NWG, 256, 0, stream>>>(x, bt, out);
}